// Round 9
// baseline (86.408 us; speedup 1.0000x reference)
//
#include <hip/hip_runtime.h>
#include <hip/hip_bf16.h>

typedef __attribute__((ext_vector_type(8))) __bf16 bf16x8;
typedef __attribute__((ext_vector_type(4))) float f32x4;

static constexpr int BROWS = 65536;
static constexpr int SDIM  = 512;
static constexpr int CDIM  = 256;
static constexpr float SLOPE = 0.01f;
static constexpr float HLP = 0.9189385332046727f;  // 0.5*log(2*pi)

// ws bf16 layout: W1T [64][512], W2T [32][64], W3T [256][32]
static constexpr int W1T_OFF = 0;
static constexpr int W2T_OFF = 64 * 512;
static constexpr int W3T_OFF = 64 * 512 + 32 * 64;
static constexpr int WS_ELEMS = W3T_OFF + 256 * 32;   // 43008

__global__ __launch_bounds__(256) void prep_weights(
    const float* __restrict__ W1, const float* __restrict__ W2,
    const float* __restrict__ W3, __bf16* __restrict__ ws)
{
    int tid = blockIdx.x * 256 + threadIdx.x;
    if (tid < 64 * 512) {                       // W1 [512][64] -> W1T [64][512]
        int n = tid >> 9, k = tid & 511;
        ws[W1T_OFF + tid] = (__bf16)W1[k * 64 + n];
    } else if (tid < 64 * 512 + 32 * 64) {      // W2 [64][32] -> W2T [32][64]
        int t = tid - 64 * 512;
        int n = t >> 6, k = t & 63;
        ws[W2T_OFF + t] = (__bf16)W2[k * 32 + n];
    } else if (tid < WS_ELEMS) {                // W3 [32][256] -> W3T [256][32]
        int t = tid - (64 * 512 + 32 * 64);
        int n = t >> 5, k = t & 31;
        ws[W3T_OFF + t] = (__bf16)W3[k * 256 + n];
    }
}

// swizzled LDS element index: row stride 64 bf16 (128B), XOR row&7 into 16B-chunk bits
__device__ __forceinline__ int swz(int row, int elem) {
    return (row * 64 + elem) ^ ((row & 7) << 3);
}

__device__ __forceinline__ bf16x8 cvt8(f32x4 a, f32x4 b) {
    bf16x8 r = {(__bf16)a.x, (__bf16)a.y, (__bf16)a.z, (__bf16)a.w,
                (__bf16)b.x, (__bf16)b.y, (__bf16)b.z, (__bf16)b.w};
    return r;
}

static constexpr int MT_STRIDE = 68;    // floats; 272-B rows, 16B-aligned
static constexpr int REGION    = 4352;  // bytes per wave: h1(2K) -> h2(2K) -> mt(4352) time-shared

// 4 waves/block, 16 rows/wave, 1024 blocks. Per-wave LDS region time-shared:
//   h1 [16][64] bf16 swz @ +0 (written then fully read by layer 2)
//   h2 [16][64] bf16 swz @ +2048 (written then read into a3 register)
//   mt [16][68] f32      @ +0 (written only after h1/h2 are dead)
// Same-wave DS ops execute in order -> no barriers, waves free-run (phase diversity).
// 17.4 KB/block + VGPR<=64 => 8 blocks/CU = 32 waves/CU (100% occupancy).
__global__ __launch_bounds__(256, 8) void policy_fused(
    const float* __restrict__ state, const float* __restrict__ b1,
    const float* __restrict__ b2, const float* __restrict__ b3,
    const float* __restrict__ noise, const __bf16* __restrict__ ws,
    float* __restrict__ actions, float* __restrict__ logp)
{
    __shared__ __align__(16) char ldsraw[4 * REGION];   // 17408 B

    const int tid  = threadIdx.x;
    const int wave = tid >> 6;
    const int lane = tid & 63;
    const int lr   = lane & 15;   // A-row / B-col index
    const int lq   = lane >> 4;   // k-chunk / C-row-quad index

    const int rowbase = blockIdx.x * 64 + wave * 16;   // this wave's 16 rows

    char* region = ldsraw + wave * REGION;
    __bf16* h1 = (__bf16*)region;             // [16][64] bf16 swz
    __bf16* h2 = (__bf16*)(region + 2048);    // [16][64] bf16 swz
    float*  mt = (float*)region;              // [16][68] f32, reuses h1+h2 space

    const __bf16* W1T = ws + W1T_OFF;
    const __bf16* W2T = ws + W2T_OFF;
    const __bf16* W3T = ws + W3T_OFF;

    const f32x4 zero4 = {0.f, 0.f, 0.f, 0.f};

    // preload tiny biases (L1/L2-hot)
    float bv1[4], bv2[2];
    #pragma unroll
    for (int n = 0; n < 4; ++n) bv1[n] = b1[n * 16 + lr];
    #pragma unroll
    for (int n = 0; n < 2; ++n) bv2[n] = b2[n * 16 + lr];

    // ---------------- layer 1: [16 rows] x [64 cols], K=512 ----------------
    f32x4 acc[4] = {zero4, zero4, zero4, zero4};
    const float* sp = state + (size_t)(rowbase + lr) * SDIM + lq * 8;
    const __bf16* wbase = W1T + lr * SDIM + lq * 8;
    #pragma unroll 4
    for (int k0 = 0; k0 < SDIM; k0 += 32) {
        f32x4 sa = *(const f32x4*)(sp + k0);
        f32x4 sb = *(const f32x4*)(sp + k0 + 4);
        bf16x8 a = cvt8(sa, sb);
        #pragma unroll
        for (int n = 0; n < 4; ++n) {
            bf16x8 b = *(const bf16x8*)(wbase + k0 + n * 16 * SDIM);
            acc[n] = __builtin_amdgcn_mfma_f32_16x16x32_bf16(a, b, acc[n], 0, 0, 0);
        }
    }
    #pragma unroll
    for (int n = 0; n < 4; ++n) {
        #pragma unroll
        for (int r = 0; r < 4; ++r) {
            float v = acc[n][r] + bv1[n];
            v = (v >= 0.f) ? v : SLOPE * v;
            h1[swz(lq * 4 + r, n * 16 + lr)] = (__bf16)v;
        }
    }

    // ---------------- layer 2: [16 rows] x [32 cols], K=64 ----------------
    f32x4 c2[2] = {zero4, zero4};
    #pragma unroll
    for (int kk = 0; kk < 2; ++kk) {
        bf16x8 a = *(const bf16x8*)&h1[swz(lr, kk * 32 + lq * 8)];
        #pragma unroll
        for (int n = 0; n < 2; ++n) {
            bf16x8 b = *(const bf16x8*)(W2T + (n * 16 + lr) * 64 + kk * 32 + lq * 8);
            c2[n] = __builtin_amdgcn_mfma_f32_16x16x32_bf16(a, b, c2[n], 0, 0, 0);
        }
    }
    #pragma unroll
    for (int n = 0; n < 2; ++n) {
        #pragma unroll
        for (int r = 0; r < 4; ++r) {
            float v = c2[n][r] + bv2[n];
            v = (v >= 0.f) ? v : SLOPE * v;
            h2[swz(lq * 4 + r, n * 16 + lr)] = (__bf16)v;
        }
    }
    bf16x8 a3 = *(const bf16x8*)&h2[swz(lr, lq * 8)];   // into regs before mt overwrites
    asm volatile("" ::: "memory");   // reuse boundary: h1/h2 dead, mt live

    // ---------------- layer 3 + epilogue, 4 groups of 64 cols ----------------
    // Read-back column mapping: col = j*16 + q*4, so each 4-lane row-group (q=0..3)
    // covers one CONTIGUOUS 64-B line per store -> full-line nontemporal stores
    // (no partial-line HBM amplification, no L3 allocation for actions).
    const int row = lane >> 2;            // 0..15 (read-back row)
    const int q   = lane & 3;             // 16-B sub-chunk within the 64-B line
    const size_t gbase = (size_t)(rowbase + row) * CDIM;
    float lp = 0.f;

    f32x4 nbuf[2][4];
    bf16x8 w3f[2][4];
    #pragma unroll
    for (int j = 0; j < 4; ++j) {
        nbuf[0][j] = *(const f32x4*)(noise + gbase + j * 16 + q * 4);
        w3f[0][j]  = *(const bf16x8*)(W3T + (j * 16 + lr) * 32 + lq * 8);
    }

    #pragma unroll
    for (int g = 0; g < 4; ++g) {
        // prefetch next group's noise + W3T frags
        if (g < 3) {
            #pragma unroll
            for (int j = 0; j < 4; ++j) {
                nbuf[(g + 1) & 1][j] = *(const f32x4*)(noise + gbase + (g + 1) * 64 + j * 16 + q * 4);
                w3f[(g + 1) & 1][j]  = *(const bf16x8*)(W3T + ((g + 1) * 64 + j * 16 + lr) * 32 + lq * 8);
            }
        }
        f32x4 b3v[4];
        #pragma unroll
        for (int j = 0; j < 4; ++j)
            b3v[j] = *(const f32x4*)(b3 + g * 64 + j * 16 + q * 4);

        // MFMA phase: 4 col-tiles -> LDS transpose buffer
        #pragma unroll
        for (int t = 0; t < 4; ++t) {
            f32x4 c = __builtin_amdgcn_mfma_f32_16x16x32_bf16(a3, w3f[g & 1][t], zero4, 0, 0, 0);
            #pragma unroll
            for (int r = 0; r < 4; ++r)
                mt[(lq * 4 + r) * MT_STRIDE + t * 16 + lr] = c[r];
        }
        // read-back phase: vectorized, contiguous per 4-lane group
        #pragma unroll
        for (int j = 0; j < 4; ++j) {
            f32x4 m4 = *(const f32x4*)&mt[row * MT_STRIDE + j * 16 + q * 4];
            f32x4 mean = m4 + b3v[j];
            f32x4 av = mean + nbuf[g & 1][j];
            __builtin_nontemporal_store(av, (f32x4*)(actions + gbase + g * 64 + j * 16 + q * 4));
            f32x4 zv = av - mean;          // replicate reference rounding exactly
            lp += -0.5f * (zv.x * zv.x + zv.y * zv.y + zv.z * zv.z + zv.w * zv.w) - 4.0f * HLP;
        }
    }
    // 4 lanes (q=0..3) share each row
    lp += __shfl_xor(lp, 1, 64);
    lp += __shfl_xor(lp, 2, 64);
    if (q == 0)
        logp[rowbase + row] = lp;
}

extern "C" void kernel_launch(void* const* d_in, const int* in_sizes, int n_in,
                              void* d_out, int out_size, void* d_ws, size_t ws_size,
                              hipStream_t stream)
{
    const float* state = (const float*)d_in[0];
    const float* W1    = (const float*)d_in[1];
    const float* b1    = (const float*)d_in[2];
    const float* W2    = (const float*)d_in[3];
    const float* b2    = (const float*)d_in[4];
    const float* W3    = (const float*)d_in[5];
    const float* b3    = (const float*)d_in[6];
    const float* noise = (const float*)d_in[7];

    if (ws_size < (size_t)WS_ELEMS * sizeof(__bf16)) return;  // need 86 KB scratch
    __bf16* ws = (__bf16*)d_ws;

    float* actions = (float*)d_out;
    float* logp    = actions + (size_t)BROWS * CDIM;

    prep_weights<<<(WS_ELEMS + 255) / 256, 256, 0, stream>>>(W1, W2, W3, ws);
    policy_fused<<<BROWS / 64, 256, 0, stream>>>(state, b1, b2, b3, noise, ws,
                                                 actions, logp);
}

// Round 10
// 69.993 us; speedup vs baseline: 1.2345x; 1.2345x over previous
//
#include <hip/hip_runtime.h>
#include <hip/hip_bf16.h>

typedef __attribute__((ext_vector_type(8))) __bf16 bf16x8;
typedef __attribute__((ext_vector_type(4))) float f32x4;

static constexpr int BROWS = 65536;
static constexpr int SDIM  = 512;
static constexpr int CDIM  = 256;
static constexpr float SLOPE = 0.01f;
static constexpr float HLP = 0.9189385332046727f;  // 0.5*log(2*pi)

// ws bf16 layout: W1T [64][512], W2T [32][64], W3T [256][32]
static constexpr int W1T_OFF = 0;
static constexpr int W2T_OFF = 64 * 512;
static constexpr int W3T_OFF = 64 * 512 + 32 * 64;
static constexpr int WS_ELEMS = W3T_OFF + 256 * 32;   // 43008

__global__ __launch_bounds__(256) void prep_weights(
    const float* __restrict__ W1, const float* __restrict__ W2,
    const float* __restrict__ W3, __bf16* __restrict__ ws)
{
    int tid = blockIdx.x * 256 + threadIdx.x;
    if (tid < 64 * 512) {                       // W1 [512][64] -> W1T [64][512]
        int n = tid >> 9, k = tid & 511;
        ws[W1T_OFF + tid] = (__bf16)W1[k * 64 + n];
    } else if (tid < 64 * 512 + 32 * 64) {      // W2 [64][32] -> W2T [32][64]
        int t = tid - 64 * 512;
        int n = t >> 6, k = t & 63;
        ws[W2T_OFF + t] = (__bf16)W2[k * 32 + n];
    } else if (tid < WS_ELEMS) {                // W3 [32][256] -> W3T [256][32]
        int t = tid - (64 * 512 + 32 * 64);
        int n = t >> 5, k = t & 31;
        ws[W3T_OFF + t] = (__bf16)W3[k * 256 + n];
    }
}

// swizzled LDS element index: row stride 64 bf16 (128B), XOR row&7 into 16B-chunk bits
__device__ __forceinline__ int swz(int row, int elem) {
    return (row * 64 + elem) ^ ((row & 7) << 3);
}

__device__ __forceinline__ bf16x8 cvt8(f32x4 a, f32x4 b) {
    bf16x8 r = {(__bf16)a.x, (__bf16)a.y, (__bf16)a.z, (__bf16)a.w,
                (__bf16)b.x, (__bf16)b.y, (__bf16)b.z, (__bf16)b.w};
    return r;
}

// mean-transpose LDS tile: per-wave 16 rows x 68-float stride (272 B rows, 16B-aligned)
static constexpr int MT_STRIDE = 68;

// Forced-issue fence: loads issued before this point cannot be sunk past it.
#define PIN_LOADS() do { \
    asm volatile("s_waitcnt vmcnt(0)" ::: "memory"); \
    __builtin_amdgcn_sched_barrier(0); \
} while (0)

__global__ __launch_bounds__(256, 4) void policy_fused(
    const float* __restrict__ state, const float* __restrict__ b1,
    const float* __restrict__ b2, const float* __restrict__ b3,
    const float* __restrict__ noise, const __bf16* __restrict__ ws,
    float* __restrict__ actions, float* __restrict__ logp)
{
    __shared__ __align__(16) __bf16 h1s[64 * 64];          // 8 KB (per-wave 16-row stripes)
    __shared__ __align__(16) __bf16 h2s[64 * 64];          // 8 KB
    __shared__ __align__(16) float  mtile[4][16 * MT_STRIDE]; // 17 KB, per-wave buffer

    const int tid  = threadIdx.x;
    const int wave = tid >> 6;
    const int lane = tid & 63;
    const int lr   = lane & 15;   // A-row / B-col index
    const int lq   = lane >> 4;   // k-chunk / C-row-quad index

    const int rowbase = blockIdx.x * 64 + wave * 16;   // this wave's 16 rows

    const __bf16* W1T = ws + W1T_OFF;
    const __bf16* W2T = ws + W2T_OFF;
    const __bf16* W3T = ws + W3T_OFF;

    const f32x4 zero4 = {0.f, 0.f, 0.f, 0.f};

    // preload tiny biases (L1/L2-hot)
    float bv1[4], bv2[2];
    #pragma unroll
    for (int n = 0; n < 4; ++n) bv1[n] = b1[n * 16 + lr];
    #pragma unroll
    for (int n = 0; n < 2; ++n) bv2[n] = b2[n * 16 + lr];

    // ---------------- layer 1: [16 rows] x [64 cols], K=512 ----------------
    // Quarter-batched state pipeline: each quarter = 4 k-iters = 8 f32x4 (32 VGPR).
    // Two quarters in flight (64 VGPR); vmcnt(0)+sched_barrier fences force the
    // batch issue (loads cannot sink past a memory-clobber asm). Each quarter's
    // L3 latency hides under the previous quarter's W-loads+MFMA compute.
    f32x4 acc[4] = {zero4, zero4, zero4, zero4};
    const float* sp = state + (size_t)(rowbase + lr) * SDIM + lq * 8;
    const __bf16* wbase = W1T + lr * SDIM + lq * 8;

    f32x4 sqA[8], sqB[8];

#define ISSUE_Q(buf, qi) \
    _Pragma("unroll") \
    for (int i = 0; i < 4; ++i) { \
        buf[2 * i]     = *(const f32x4*)(sp + ((qi) * 4 + i) * 32); \
        buf[2 * i + 1] = *(const f32x4*)(sp + ((qi) * 4 + i) * 32 + 4); \
    }

#define COMPUTE_Q(buf, qi) \
    _Pragma("unroll") \
    for (int i = 0; i < 4; ++i) { \
        bf16x8 a = cvt8(buf[2 * i], buf[2 * i + 1]); \
        _Pragma("unroll") \
        for (int n = 0; n < 4; ++n) { \
            bf16x8 b = *(const bf16x8*)(wbase + ((qi) * 4 + i) * 32 + n * 16 * SDIM); \
            acc[n] = __builtin_amdgcn_mfma_f32_16x16x32_bf16(a, b, acc[n], 0, 0, 0); \
        } \
    }

    ISSUE_Q(sqA, 0);
    PIN_LOADS();
    ISSUE_Q(sqB, 1);
    COMPUTE_Q(sqA, 0);
    PIN_LOADS();
    ISSUE_Q(sqA, 2);
    COMPUTE_Q(sqB, 1);
    PIN_LOADS();
    ISSUE_Q(sqB, 3);
    COMPUTE_Q(sqA, 2);
    PIN_LOADS();
    COMPUTE_Q(sqB, 3);

#undef ISSUE_Q
#undef COMPUTE_Q

    #pragma unroll
    for (int n = 0; n < 4; ++n) {
        #pragma unroll
        for (int r = 0; r < 4; ++r) {
            float v = acc[n][r] + bv1[n];
            v = (v >= 0.f) ? v : SLOPE * v;
            int row = wave * 16 + lq * 4 + r;
            h1s[swz(row, n * 16 + lr)] = (__bf16)v;
        }
    }
    // no __syncthreads(): each wave touches only its own 16-row stripe (in-order DS)

    // ---------------- layer 2: [16 rows] x [32 cols], K=64 ----------------
    f32x4 c2[2] = {zero4, zero4};
    #pragma unroll
    for (int kk = 0; kk < 2; ++kk) {
        bf16x8 a = *(const bf16x8*)&h1s[swz(wave * 16 + lr, kk * 32 + lq * 8)];
        #pragma unroll
        for (int n = 0; n < 2; ++n) {
            bf16x8 b = *(const bf16x8*)(W2T + (n * 16 + lr) * 64 + kk * 32 + lq * 8);
            c2[n] = __builtin_amdgcn_mfma_f32_16x16x32_bf16(a, b, c2[n], 0, 0, 0);
        }
    }
    #pragma unroll
    for (int n = 0; n < 2; ++n) {
        #pragma unroll
        for (int r = 0; r < 4; ++r) {
            float v = c2[n][r] + bv2[n];
            v = (v >= 0.f) ? v : SLOPE * v;
            int row = wave * 16 + lq * 4 + r;
            h2s[swz(row, n * 16 + lr)] = (__bf16)v;
        }
    }

    // ---------------- layer 3 + epilogue, 4 groups of 64 cols ----------------
    // Read-back column mapping: col = j*16 + q*4, so each 4-lane row-group (q=0..3)
    // covers one CONTIGUOUS 64-B line per store -> full-line nontemporal stores
    // (no partial-line HBM amplification, no L3 allocation for actions).
    bf16x8 a3 = *(const bf16x8*)&h2s[swz(wave * 16 + lr, lq * 8)];
    float* mt = &mtile[wave][0];
    const int row = lane >> 2;            // 0..15 (read-back row)
    const int q   = lane & 3;             // 16-B sub-chunk within the 64-B line
    const size_t gbase = (size_t)(rowbase + row) * CDIM;
    float lp = 0.f;

    f32x4 nbuf[2][4];
    bf16x8 w3f[2][4];
    #pragma unroll
    for (int j = 0; j < 4; ++j) {
        nbuf[0][j] = *(const f32x4*)(noise + gbase + j * 16 + q * 4);
        w3f[0][j]  = *(const bf16x8*)(W3T + (j * 16 + lr) * 32 + lq * 8);
    }

    #pragma unroll
    for (int g = 0; g < 4; ++g) {
        // prefetch next group's noise + W3T frags
        if (g < 3) {
            #pragma unroll
            for (int j = 0; j < 4; ++j) {
                nbuf[(g + 1) & 1][j] = *(const f32x4*)(noise + gbase + (g + 1) * 64 + j * 16 + q * 4);
                w3f[(g + 1) & 1][j]  = *(const bf16x8*)(W3T + ((g + 1) * 64 + j * 16 + lr) * 32 + lq * 8);
            }
        }
        f32x4 b3v[4];
        #pragma unroll
        for (int j = 0; j < 4; ++j)
            b3v[j] = *(const f32x4*)(b3 + g * 64 + j * 16 + q * 4);

        // MFMA phase: 4 col-tiles -> per-wave LDS transpose buffer
        #pragma unroll
        for (int t = 0; t < 4; ++t) {
            f32x4 c = __builtin_amdgcn_mfma_f32_16x16x32_bf16(a3, w3f[g & 1][t], zero4, 0, 0, 0);
            #pragma unroll
            for (int r = 0; r < 4; ++r)
                mt[(lq * 4 + r) * MT_STRIDE + t * 16 + lr] = c[r];
        }
        // read-back phase: vectorized, contiguous per 4-lane group
        #pragma unroll
        for (int j = 0; j < 4; ++j) {
            f32x4 m4 = *(const f32x4*)&mt[row * MT_STRIDE + j * 16 + q * 4];
            f32x4 mean = m4 + b3v[j];
            f32x4 av = mean + nbuf[g & 1][j];
            __builtin_nontemporal_store(av, (f32x4*)(actions + gbase + g * 64 + j * 16 + q * 4));
            f32x4 zv = av - mean;          // replicate reference rounding exactly
            lp += -0.5f * (zv.x * zv.x + zv.y * zv.y + zv.z * zv.z + zv.w * zv.w) - 4.0f * HLP;
        }
    }
    // 4 lanes (q=0..3) share each row
    lp += __shfl_xor(lp, 1, 64);
    lp += __shfl_xor(lp, 2, 64);
    if (q == 0)
        logp[rowbase + row] = lp;
}

extern "C" void kernel_launch(void* const* d_in, const int* in_sizes, int n_in,
                              void* d_out, int out_size, void* d_ws, size_t ws_size,
                              hipStream_t stream)
{
    const float* state = (const float*)d_in[0];
    const float* W1    = (const float*)d_in[1];
    const float* b1    = (const float*)d_in[2];
    const float* W2    = (const float*)d_in[3];
    const float* b2    = (const float*)d_in[4];
    const float* W3    = (const float*)d_in[5];
    const float* b3    = (const float*)d_in[6];
    const float* noise = (const float*)d_in[7];

    if (ws_size < (size_t)WS_ELEMS * sizeof(__bf16)) return;  // need 86 KB scratch
    __bf16* ws = (__bf16*)d_ws;

    float* actions = (float*)d_out;
    float* logp    = actions + (size_t)BROWS * CDIM;

    prep_weights<<<(WS_ELEMS + 255) / 256, 256, 0, stream>>>(W1, W2, W3, ws);
    policy_fused<<<BROWS / 64, 256, 0, stream>>>(state, b1, b2, b3, noise, ws,
                                                 actions, logp);
}

// Round 11
// 60.823 us; speedup vs baseline: 1.4206x; 1.1508x over previous
//
#include <hip/hip_runtime.h>
#include <hip/hip_bf16.h>

typedef __attribute__((ext_vector_type(8))) __bf16 bf16x8;
typedef __attribute__((ext_vector_type(4))) float f32x4;

static constexpr int BROWS = 65536;
static constexpr int SDIM  = 512;
static constexpr int CDIM  = 256;
static constexpr float SLOPE = 0.01f;
static constexpr float HLP = 0.9189385332046727f;  // 0.5*log(2*pi)

// ws bf16 layout: W1T [64][512], W2T [32][64], W3T [256][32]
static constexpr int W1T_OFF = 0;
static constexpr int W2T_OFF = 64 * 512;
static constexpr int W3T_OFF = 64 * 512 + 32 * 64;
static constexpr int WS_ELEMS = W3T_OFF + 256 * 32;   // 43008

__global__ __launch_bounds__(256) void prep_weights(
    const float* __restrict__ W1, const float* __restrict__ W2,
    const float* __restrict__ W3, __bf16* __restrict__ ws)
{
    int tid = blockIdx.x * 256 + threadIdx.x;
    if (tid < 64 * 512) {                       // W1 [512][64] -> W1T [64][512]
        int n = tid >> 9, k = tid & 511;
        ws[W1T_OFF + tid] = (__bf16)W1[k * 64 + n];
    } else if (tid < 64 * 512 + 32 * 64) {      // W2 [64][32] -> W2T [32][64]
        int t = tid - 64 * 512;
        int n = t >> 6, k = t & 63;
        ws[W2T_OFF + t] = (__bf16)W2[k * 32 + n];
    } else if (tid < WS_ELEMS) {                // W3 [32][256] -> W3T [256][32]
        int t = tid - (64 * 512 + 32 * 64);
        int n = t >> 5, k = t & 31;
        ws[W3T_OFF + t] = (__bf16)W3[k * 256 + n];
    }
}

// swizzled LDS element index for bf16 [16][64] tiles: row stride 128 B
__device__ __forceinline__ int swz(int row, int elem) {
    return (row * 64 + elem) ^ ((row & 7) << 3);
}

__device__ __forceinline__ bf16x8 cvt8(f32x4 a, f32x4 b) {
    bf16x8 r = {(__bf16)a.x, (__bf16)a.y, (__bf16)a.z, (__bf16)a.w,
                (__bf16)b.x, (__bf16)b.y, (__bf16)b.z, (__bf16)b.w};
    return r;
}

static constexpr int MT_STRIDE = 68;     // floats
// Per-wave LDS region: two 4352-B state-chunk DMA buffers (4 row-groups x 1088 B).
// After layer 1, buf0 is reused for h1(2K)+h2(2K), buf1 for mt (16x68 f32 = 4352 B).
static constexpr int WREGION = 8704;

// 4 waves/block, 16 rows/wave, 1024 blocks, ~34.8 KB LDS -> 4 blocks/CU (16 waves).
// Layer-1 state is streamed by global_load_lds in 8 K-chunks (64 floats/row = 4 KB),
// depth-1 double-buffered with counted s_waitcnt vmcnt(12) (never 0 until the tail):
// the next chunk's 64 cache lines are ALWAYS in flight while the current chunk
// computes -> per-CU request queue saturated (vs ~3 lines/wave with VGPR buffering).
// DMA source is pre-swizzled (slot ^ row&7) so the LDS A-frag reads are spread
// across bank groups (T21: linear dest + inverse-swizzled source + swizzled read).
__global__ __launch_bounds__(256, 4) void policy_fused(
    const float* __restrict__ state, const float* __restrict__ b1,
    const float* __restrict__ b2, const float* __restrict__ b3,
    const float* __restrict__ noise, const __bf16* __restrict__ ws,
    float* __restrict__ actions, float* __restrict__ logp)
{
    __shared__ __align__(64) char ldsraw[4 * WREGION];   // 34816 B

    const int tid  = threadIdx.x;
    const int wave = tid >> 6;
    const int lane = tid & 63;
    const int lr   = lane & 15;   // A-row / B-col index
    const int lq   = lane >> 4;   // k-chunk / C-row-quad index

    const int rowbase = blockIdx.x * 64 + wave * 16;   // this wave's 16 rows

    char* region = ldsraw + wave * WREGION;

    const __bf16* W1T = ws + W1T_OFF;
    const __bf16* W2T = ws + W2T_OFF;
    const __bf16* W3T = ws + W3T_OFF;

    const f32x4 zero4 = {0.f, 0.f, 0.f, 0.f};

    // preload tiny biases (older than all counted ops -> doesn't disturb vmcnt math)
    float bv1[4], bv2[2];
    #pragma unroll
    for (int n = 0; n < 4; ++n) bv1[n] = b1[n * 16 + lr];
    #pragma unroll
    for (int n = 0; n < 2; ++n) bv2[n] = b2[n * 16 + lr];

    // ---------------- layer 1: DMA-pipelined, 8 chunks of K=64 ----------------
    // DMA_CHUNK: 4 global_load_lds x 1 KB. Instr i covers rows 4i..4i+3
    // (lane = r*16 + s: row-in-group r = lane>>4, 16-B slot s = lane&15).
    // Source slot pre-swizzled: s_g = s ^ (row & 7). LDS dest linear at i*1088.
    const int dma_row = lane >> 4;          // 0..3 within group
    const int dma_s   = lane & 15;          // 16-B slot

#define DMA_CHUNK(c, bufofs) do { \
    _Pragma("unroll") \
    for (int i = 0; i < 4; ++i) { \
        int row = i * 4 + dma_row; \
        int sx  = dma_s ^ (row & 7); \
        const float* src = state + (size_t)(rowbase + row) * SDIM + (c) * 64 + sx * 4; \
        __builtin_amdgcn_global_load_lds( \
            (const __attribute__((address_space(1))) void*)src, \
            (__attribute__((address_space(3))) void*)(region + (bufofs) + i * 1088), \
            16, 0, 0); \
    } } while (0)

#define WLOAD(c, wbuf) do { \
    _Pragma("unroll") \
    for (int n = 0; n < 4; ++n) { \
        _Pragma("unroll") \
        for (int ks = 0; ks < 2; ++ks) \
            wbuf[n * 2 + ks] = *(const bf16x8*)(W1T + (n * 16 + lr) * SDIM + (c) * 64 + ks * 32 + lq * 8); \
    } } while (0)

    const int rbase = (lr >> 2) * 1088 + (lr & 3) * 256;   // this lane's row base in a chunk buf
    const int xr    = lr & 7;

#define COMPUTE(bufofs, wbuf) do { \
    _Pragma("unroll") \
    for (int ks = 0; ks < 2; ++ks) { \
        f32x4 a0 = *(const f32x4*)(region + (bufofs) + rbase + (((ks * 8 + lq * 2 + 0) ^ xr) * 16)); \
        f32x4 a1 = *(const f32x4*)(region + (bufofs) + rbase + (((ks * 8 + lq * 2 + 1) ^ xr) * 16)); \
        bf16x8 a = cvt8(a0, a1); \
        _Pragma("unroll") \
        for (int n = 0; n < 4; ++n) \
            acc[n] = __builtin_amdgcn_mfma_f32_16x16x32_bf16(a, wbuf[n * 2 + ks], acc[n], 0, 0, 0); \
    } } while (0)

    f32x4 acc[4] = {zero4, zero4, zero4, zero4};
    bf16x8 w1fA[8], w1fB[8];

    // prologue: chunks 0 and 1 in flight (12 counted ops each: 4 DMA + 8 W)
    DMA_CHUNK(0, 0);
    WLOAD(0, w1fA);
    DMA_CHUNK(1, 4352);
    WLOAD(1, w1fB);

    #pragma unroll
    for (int k = 0; k < 8; ++k) {
        // wait: newest 12 outstanding = chunk k+1's DMA+W  =>  chunk k fully landed
        if (k == 7) asm volatile("s_waitcnt vmcnt(0)" ::: "memory");
        else        asm volatile("s_waitcnt vmcnt(12)" ::: "memory");
        __builtin_amdgcn_sched_barrier(0);
        if (k & 1) COMPUTE(4352, w1fB);
        else       COMPUTE(0,    w1fA);
        if (k < 6) {   // refill the buffer just consumed (ds_reads already drained)
            if (k & 1) { DMA_CHUNK(k + 2, 4352); WLOAD(k + 2, w1fB); }
            else       { DMA_CHUNK(k + 2, 0);    WLOAD(k + 2, w1fA); }
        }
    }
#undef DMA_CHUNK
#undef WLOAD
#undef COMPUTE

    // state buffers dead; overlay h1/h2 on buf0, mt on buf1
    __bf16* h1 = (__bf16*)region;             // [16][64] bf16 swz, 2 KB
    __bf16* h2 = (__bf16*)(region + 2048);    // [16][64] bf16 swz, 2 KB
    float*  mt = (float*)(region + 4352);     // [16][68] f32, 4352 B

    #pragma unroll
    for (int n = 0; n < 4; ++n) {
        #pragma unroll
        for (int r = 0; r < 4; ++r) {
            float v = acc[n][r] + bv1[n];
            v = (v >= 0.f) ? v : SLOPE * v;
            h1[swz(lq * 4 + r, n * 16 + lr)] = (__bf16)v;
        }
    }

    // ---------------- layer 2: [16 rows] x [32 cols], K=64 ----------------
    f32x4 c2[2] = {zero4, zero4};
    #pragma unroll
    for (int kk = 0; kk < 2; ++kk) {
        bf16x8 a = *(const bf16x8*)&h1[swz(lr, kk * 32 + lq * 8)];
        #pragma unroll
        for (int n = 0; n < 2; ++n) {
            bf16x8 b = *(const bf16x8*)(W2T + (n * 16 + lr) * 64 + kk * 32 + lq * 8);
            c2[n] = __builtin_amdgcn_mfma_f32_16x16x32_bf16(a, b, c2[n], 0, 0, 0);
        }
    }
    #pragma unroll
    for (int n = 0; n < 2; ++n) {
        #pragma unroll
        for (int r = 0; r < 4; ++r) {
            float v = c2[n][r] + bv2[n];
            v = (v >= 0.f) ? v : SLOPE * v;
            h2[swz(lq * 4 + r, n * 16 + lr)] = (__bf16)v;
        }
    }
    bf16x8 a3 = *(const bf16x8*)&h2[swz(lr, lq * 8)];   // into regs before mt use
    asm volatile("" ::: "memory");

    // ---------------- layer 3 + epilogue, 4 groups of 64 cols ----------------
    // Read-back column mapping: col = j*16 + q*4 -> each 4-lane row-group covers one
    // CONTIGUOUS 64-B line per nt store (no partial-line amplification, no L3 alloc).
    const int row = lane >> 2;            // 0..15 (read-back row)
    const int q   = lane & 3;             // 16-B sub-chunk within the 64-B line
    const size_t gbase = (size_t)(rowbase + row) * CDIM;
    float lp = 0.f;

    f32x4 nbuf[2][4];
    bf16x8 w3f[2][4];
    #pragma unroll
    for (int j = 0; j < 4; ++j) {
        nbuf[0][j] = *(const f32x4*)(noise + gbase + j * 16 + q * 4);
        w3f[0][j]  = *(const bf16x8*)(W3T + (j * 16 + lr) * 32 + lq * 8);
    }

    #pragma unroll
    for (int g = 0; g < 4; ++g) {
        if (g < 3) {
            #pragma unroll
            for (int j = 0; j < 4; ++j) {
                nbuf[(g + 1) & 1][j] = *(const f32x4*)(noise + gbase + (g + 1) * 64 + j * 16 + q * 4);
                w3f[(g + 1) & 1][j]  = *(const bf16x8*)(W3T + ((g + 1) * 64 + j * 16 + lr) * 32 + lq * 8);
            }
        }
        f32x4 b3v[4];
        #pragma unroll
        for (int j = 0; j < 4; ++j)
            b3v[j] = *(const f32x4*)(b3 + g * 64 + j * 16 + q * 4);

        // MFMA phase: 4 col-tiles -> LDS transpose buffer
        #pragma unroll
        for (int t = 0; t < 4; ++t) {
            f32x4 c = __builtin_amdgcn_mfma_f32_16x16x32_bf16(a3, w3f[g & 1][t], zero4, 0, 0, 0);
            #pragma unroll
            for (int r = 0; r < 4; ++r)
                mt[(lq * 4 + r) * MT_STRIDE + t * 16 + lr] = c[r];
        }
        // read-back phase: vectorized, contiguous per 4-lane group
        #pragma unroll
        for (int j = 0; j < 4; ++j) {
            f32x4 m4 = *(const f32x4*)&mt[row * MT_STRIDE + j * 16 + q * 4];
            f32x4 mean = m4 + b3v[j];
            f32x4 av = mean + nbuf[g & 1][j];
            __builtin_nontemporal_store(av, (f32x4*)(actions + gbase + g * 64 + j * 16 + q * 4));
            f32x4 zv = av - mean;          // replicate reference rounding exactly
            lp += -0.5f * (zv.x * zv.x + zv.y * zv.y + zv.z * zv.z + zv.w * zv.w) - 4.0f * HLP;
        }
    }
    // 4 lanes (q=0..3) share each row
    lp += __shfl_xor(lp, 1, 64);
    lp += __shfl_xor(lp, 2, 64);
    if (q == 0)
        logp[rowbase + row] = lp;
}

extern "C" void kernel_launch(void* const* d_in, const int* in_sizes, int n_in,
                              void* d_out, int out_size, void* d_ws, size_t ws_size,
                              hipStream_t stream)
{
    const float* state = (const float*)d_in[0];
    const float* W1    = (const float*)d_in[1];
    const float* b1    = (const float*)d_in[2];
    const float* W2    = (const float*)d_in[3];
    const float* b2    = (const float*)d_in[4];
    const float* W3    = (const float*)d_in[5];
    const float* b3    = (const float*)d_in[6];
    const float* noise = (const float*)d_in[7];

    if (ws_size < (size_t)WS_ELEMS * sizeof(__bf16)) return;  // need 86 KB scratch
    __bf16* ws = (__bf16*)d_ws;

    float* actions = (float*)d_out;
    float* logp    = actions + (size_t)BROWS * CDIM;

    prep_weights<<<(WS_ELEMS + 255) / 256, 256, 0, stream>>>(W1, W2, W3, ws);
    policy_fused<<<BROWS / 64, 256, 0, stream>>>(state, b1, b2, b3, noise, ws,
                                                 actions, logp);
}